// Round 1
// baseline (21115.749 us; speedup 1.0000x reference)
//
#include <hip/hip_runtime.h>
#include <hip/hip_bf16.h>
#include <math.h>

// Problem constants
static constexpr int kV = 32000;
static constexpr int kD = 768;
static constexpr int kH = 12;
static constexpr int kL = 6;
static constexpr int kF = 3072;
static constexpr int kS = 2048;
static constexpr int kB = 4;
static constexpr int kDK = 64;

// ---------------------------------------------------------------------------
// Embedding + sinusoidal positional encoding
// x[t,d] = emb[ids[t],d] + PE(s,d);  PE[s,2i]=sin(s*div_i), PE[s,2i+1]=cos(...)
// ---------------------------------------------------------------------------
__global__ __launch_bounds__(256) void embed_pe(
    const int* __restrict__ ids, const float* __restrict__ emb,
    float* __restrict__ x)
{
    const int t = blockIdx.x;          // token index 0..B*S-1
    const int s = t & (kS - 1);        // position within sequence
    const int id = ids[t];
#pragma unroll
    for (int j = 0; j < 3; ++j) {
        const int d = threadIdx.x + (j << 8);
        const float i2 = (float)((d >> 1) << 1);                 // 2*i
        const float dv = __expf(i2 * (-9.210340371976184f / 768.f)); // ln(10000)
        const float ang = (float)s * dv;
        const float pe = (d & 1) ? cosf(ang) : sinf(ang);
        x[(size_t)t * kD + d] = emb[(size_t)id * kD + d] + pe;
    }
}

// ---------------------------------------------------------------------------
// f32 tiled GEMM: C[M,N] = A[M,K] @ W[K,N] + bias[N]  (optional ReLU)
// 64x64 tile, BK=16, 256 threads, 4x4 acc per thread, float4 LDS reads.
// ---------------------------------------------------------------------------
__global__ __launch_bounds__(256) void gemm_f32(
    const float* __restrict__ A, const float* __restrict__ W,
    const float* __restrict__ bias, float* __restrict__ C,
    int M, int N, int K, int relu)
{
    __shared__ float As[16][68];   // transposed A tile: As[k][m], padded (+4 keeps 16B align)
    __shared__ float Bs[16][68];   // Bs[k][n]

    const int tid  = threadIdx.x;
    const int row0 = blockIdx.x << 6;
    const int col0 = blockIdx.y << 6;
    const int tx = tid & 15, ty = tid >> 4;

    const int ar = tid >> 2;            // A-load row   0..63
    const int ak = (tid & 3) << 2;      // A-load k     0,4,8,12
    const int bk = tid >> 4;            // B-load k     0..15
    const int bc = (tid & 15) << 2;     // B-load col   0..60

    float acc[4][4] = {};

    const float* Ap = A + (size_t)(row0 + ar) * K + ak;
    const float* Wp = W + (size_t)bk * N + col0 + bc;

    for (int k0 = 0; k0 < K; k0 += 16) {
        const float4 a4 = *(const float4*)(Ap + k0);
        const float4 b4 = *(const float4*)(Wp + (size_t)k0 * N);
        __syncthreads();
        As[ak + 0][ar] = a4.x;
        As[ak + 1][ar] = a4.y;
        As[ak + 2][ar] = a4.z;
        As[ak + 3][ar] = a4.w;
        *(float4*)&Bs[bk][bc] = b4;
        __syncthreads();
#pragma unroll
        for (int kk = 0; kk < 16; ++kk) {
            const float4 av = *(const float4*)&As[kk][ty << 2];
            const float4 bv = *(const float4*)&Bs[kk][tx << 2];
            const float aa[4] = {av.x, av.y, av.z, av.w};
            const float bb[4] = {bv.x, bv.y, bv.z, bv.w};
#pragma unroll
            for (int i = 0; i < 4; ++i)
#pragma unroll
                for (int j = 0; j < 4; ++j)
                    acc[i][j] = fmaf(aa[i], bb[j], acc[i][j]);
        }
    }

#pragma unroll
    for (int i = 0; i < 4; ++i) {
        const int row = row0 + (ty << 2) + i;
#pragma unroll
        for (int j = 0; j < 4; ++j) {
            const int col = col0 + (tx << 2) + j;
            float v = acc[i][j] + bias[col];
            if (relu) v = fmaxf(v, 0.f);
            C[(size_t)row * N + col] = v;
        }
    }
}

// ---------------------------------------------------------------------------
// Fused attention (flash-style, online softmax), f32.
// Block = 256 threads = 4 waves. Each wave owns 4 query rows; block shares
// K/V 64-key LDS tiles. Lane owns key for QK^T, lane owns dim for PV.
// XOR swizzle on float4 slots keeps ds_read_b128 conflict-free.
// Grid: (S/16, H, B)
// ---------------------------------------------------------------------------
__global__ __launch_bounds__(256) void attn_fused(
    const float* __restrict__ Q, const float* __restrict__ Km,
    const float* __restrict__ Vm, const int* __restrict__ ids,
    float* __restrict__ O)
{
    __shared__ float Ks[64 * 64];     // [key][d], slot-swizzled
    __shared__ float Vt[64 * 64];     // [d][key], slot-swizzled
    __shared__ float Qs[16][64];      // 16 query rows, pre-scaled by 1/8
    __shared__ float Ps[4][4][64];    // per wave, per row: p over 64 keys

    const int tid  = threadIdx.x;
    const int w    = tid >> 6;
    const int lane = tid & 63;
    const int h = blockIdx.y, b = blockIdx.z;
    const int qrow0 = blockIdx.x << 4;

    {   // load Q tile: 16 rows x 64 dims
        const int r  = tid >> 4;
        const int c4 = tid & 15;
        const float4 q4 = *(const float4*)(
            Q + ((size_t)(b * kS + qrow0 + r)) * kD + h * 64 + (c4 << 2));
        Qs[r][(c4 << 2) + 0] = q4.x * 0.125f;
        Qs[r][(c4 << 2) + 1] = q4.y * 0.125f;
        Qs[r][(c4 << 2) + 2] = q4.z * 0.125f;
        Qs[r][(c4 << 2) + 3] = q4.w * 0.125f;
    }

    float m[4], l[4], o[4];
#pragma unroll
    for (int r = 0; r < 4; ++r) { m[r] = -3.0e38f; l[r] = 0.f; o[r] = 0.f; }

    for (int kt = 0; kt < kS / 64; ++kt) {
        __syncthreads();
        // ---- stage K (row-major, swizzled) and V (transposed, swizzled) ----
#pragma unroll
        for (int i = 0; i < 4; ++i) {
            const int lin = tid + (i << 8);
            const int row = lin >> 4;       // key within tile
            const int s4  = lin & 15;       // float4 slot along d
            const size_t gro =
                ((size_t)(b * kS + (kt << 6) + row)) * kD + h * 64 + (s4 << 2);
            const float4 k4 = *(const float4*)(Km + gro);
            ((float4*)Ks)[(row << 4) + (s4 ^ (row & 7))] = k4;
            const float4 v4 = *(const float4*)(Vm + gro);
            const int ksl = row >> 2, ke = row & 3;
            const int d0  = s4 << 2;
            Vt[(d0 + 0) * 64 + ((ksl ^ ((d0 + 0) & 7)) << 2) + ke] = v4.x;
            Vt[(d0 + 1) * 64 + ((ksl ^ ((d0 + 1) & 7)) << 2) + ke] = v4.y;
            Vt[(d0 + 2) * 64 + ((ksl ^ ((d0 + 2) & 7)) << 2) + ke] = v4.z;
            Vt[(d0 + 3) * 64 + ((ksl ^ ((d0 + 3) & 7)) << 2) + ke] = v4.w;
        }
        __syncthreads();

        // ---- scores: lane owns key = kt*64 + lane ----
        const bool masked = (ids[(size_t)b * kS + (kt << 6) + lane] == 1);
        float scr[4] = {0.f, 0.f, 0.f, 0.f};
#pragma unroll
        for (int i16 = 0; i16 < 16; ++i16) {
            const float4 kv = ((const float4*)Ks)[(lane << 4) + (i16 ^ (lane & 7))];
#pragma unroll
            for (int r = 0; r < 4; ++r) {
                const float4 qv = *(const float4*)&Qs[(w << 2) + r][i16 << 2];
                scr[r] = fmaf(kv.x, qv.x,
                          fmaf(kv.y, qv.y,
                           fmaf(kv.z, qv.z,
                            fmaf(kv.w, qv.w, scr[r]))));
            }
        }
        // ---- online softmax update per row ----
#pragma unroll
        for (int r = 0; r < 4; ++r) {
            float sm = masked ? -3.0e38f : scr[r];
#pragma unroll
            for (int off = 32; off; off >>= 1) sm = fmaxf(sm, __shfl_xor(sm, off));
            const float mn = fmaxf(m[r], sm);
            const float corr = __expf(m[r] - mn);
            const float p = masked ? 0.f : __expf(scr[r] - mn);
            float ps = p;
#pragma unroll
            for (int off = 32; off; off >>= 1) ps += __shfl_xor(ps, off);
            l[r] = l[r] * corr + ps;
            o[r] *= corr;
            m[r] = mn;
            Ps[w][r][lane] = p;   // same-wave LDS ops are in-order
        }
        // ---- PV: lane owns output dim = lane ----
#pragma unroll
        for (int i16 = 0; i16 < 16; ++i16) {
            const float4 vv = ((const float4*)Vt)[(lane << 4) + (i16 ^ (lane & 7))];
#pragma unroll
            for (int r = 0; r < 4; ++r) {
                const float4 pv = *(const float4*)&Ps[w][r][i16 << 2];
                o[r] = fmaf(pv.x, vv.x,
                        fmaf(pv.y, vv.y,
                         fmaf(pv.z, vv.z,
                          fmaf(pv.w, vv.w, o[r]))));
            }
        }
    }

#pragma unroll
    for (int r = 0; r < 4; ++r)
        O[((size_t)(b * kS + qrow0 + (w << 2) + r)) * kD + h * 64 + lane] =
            o[r] / l[r];
}

// ---------------------------------------------------------------------------
// out = LayerNorm(a + r) * g + bt     (one block per row of 768)
// ---------------------------------------------------------------------------
__device__ __forceinline__ float block_sum(float v, float* red)
{
#pragma unroll
    for (int off = 32; off; off >>= 1) v += __shfl_xor(v, off);
    __syncthreads();
    if ((threadIdx.x & 63) == 0) red[threadIdx.x >> 6] = v;
    __syncthreads();
    return red[0] + red[1] + red[2] + red[3];
}

__global__ __launch_bounds__(256) void add_ln(
    const float* __restrict__ a, const float* __restrict__ r,
    const float* __restrict__ g, const float* __restrict__ bt,
    float* __restrict__ out)
{
    __shared__ float red[4];
    const size_t row = blockIdx.x;
    const int tid = threadIdx.x;
    float v[3];
    float s = 0.f;
#pragma unroll
    for (int j = 0; j < 3; ++j) {
        const int d = tid + (j << 8);
        v[j] = a[row * kD + d] + r[row * kD + d];
        s += v[j];
    }
    s = block_sum(s, red);
    const float mu = s * (1.f / 768.f);
    float vs = 0.f;
#pragma unroll
    for (int j = 0; j < 3; ++j) { const float t = v[j] - mu; vs = fmaf(t, t, vs); }
    vs = block_sum(vs, red);
    const float rstd = rsqrtf(vs * (1.f / 768.f) + 1e-5f);
#pragma unroll
    for (int j = 0; j < 3; ++j) {
        const int d = tid + (j << 8);
        out[row * kD + d] = (v[j] - mu) * rstd * g[d] + bt[d];
    }
}

// ---------------------------------------------------------------------------
// out[b,d] = mean over s of x[b,s,d]       grid: (D/256, B)
// ---------------------------------------------------------------------------
__global__ __launch_bounds__(256) void mean_s(
    const float* __restrict__ x, float* __restrict__ out)
{
    const int d = blockIdx.x * 256 + threadIdx.x;
    const int b = blockIdx.y;
    float s = 0.f;
    for (int t = 0; t < kS; ++t) s += x[((size_t)b * kS + t) * kD + d];
    out[b * kD + d] = s * (1.f / 2048.f);
}

// ---------------------------------------------------------------------------
// Host orchestration
// ---------------------------------------------------------------------------
extern "C" void kernel_launch(void* const* d_in, const int* in_sizes, int n_in,
                              void* d_out, int out_size, void* d_ws, size_t ws_size,
                              hipStream_t stream)
{
    const int*   ids   = (const int*)  d_in[0];
    const float* emb   = (const float*)d_in[1];
    const float* Wq    = (const float*)d_in[2];
    const float* bq    = (const float*)d_in[3];
    const float* Wk    = (const float*)d_in[4];
    const float* bk    = (const float*)d_in[5];
    const float* Wv    = (const float*)d_in[6];
    const float* bv    = (const float*)d_in[7];
    const float* Wo    = (const float*)d_in[8];
    const float* bo    = (const float*)d_in[9];
    const float* W1    = (const float*)d_in[10];
    const float* b1    = (const float*)d_in[11];
    const float* W2    = (const float*)d_in[12];
    const float* b2    = (const float*)d_in[13];
    const float* gamma = (const float*)d_in[14];
    const float* beta  = (const float*)d_in[15];
    float* out = (float*)d_out;

    const size_t BUFE = (size_t)kB * kS * kD;        // 6,291,456 elems (25.2 MB)
    if (ws_size < 5 * BUFE * sizeof(float)) return;  // need ~126 MB scratch

    float* xb = (float*)d_ws;        // x (residual stream)
    float* kb = xb + BUFE;           // K matrix, later x1
    float* qb = kb + BUFE;           // Q matrix, later o_proj, later FFN-hidden lo
    float* vb = qb + BUFE;           // V matrix, later FFN-hidden hi
    float* ob = vb + BUFE;           // attn out, later FFN out
    float* hb = qb;                  // FFN hidden chunk: spans qb..vb (50 MB)

    const int NTOK = kB * kS;        // 8192

    embed_pe<<<NTOK, 256, 0, stream>>>(ids, emb, xb);

    for (int l = 0; l < kL; ++l) {
        const size_t oDD = (size_t)l * kD * kD;
        const size_t oDF = (size_t)l * kD * kF;

        // QKV projections
        gemm_f32<<<dim3(NTOK / 64, kD / 64), 256, 0, stream>>>(
            xb, Wq + oDD, bq + (size_t)l * kD, qb, NTOK, kD, kD, 0);
        gemm_f32<<<dim3(NTOK / 64, kD / 64), 256, 0, stream>>>(
            xb, Wk + oDD, bk + (size_t)l * kD, kb, NTOK, kD, kD, 0);
        gemm_f32<<<dim3(NTOK / 64, kD / 64), 256, 0, stream>>>(
            xb, Wv + oDD, bv + (size_t)l * kD, vb, NTOK, kD, kD, 0);

        // fused attention
        attn_fused<<<dim3(kS / 16, kH, kB), 256, 0, stream>>>(qb, kb, vb, ids, ob);

        // output projection -> qb
        gemm_f32<<<dim3(NTOK / 64, kD / 64), 256, 0, stream>>>(
            ob, Wo + oDD, bo + (size_t)l * kD, qb, NTOK, kD, kD, 0);

        // x1 = LN(x + o_proj) -> kb
        add_ln<<<NTOK, 256, 0, stream>>>(xb, qb,
            gamma + (size_t)l * kD, beta + (size_t)l * kD, kb);

        // FFN in two row-chunks of 4096 (hidden reuses qb+vb = 50 MB)
        for (int c = 0; c < 2; ++c) {
            const size_t ro = (size_t)c * 4096;
            gemm_f32<<<dim3(4096 / 64, kF / 64), 256, 0, stream>>>(
                kb + ro * kD, W1 + oDF, b1 + (size_t)l * kF, hb,
                4096, kF, kD, 1);
            gemm_f32<<<dim3(4096 / 64, kD / 64), 256, 0, stream>>>(
                hb, W2 + oDF, b2 + (size_t)l * kD, ob + ro * kD,
                4096, kD, kF, 0);
        }

        // x = LN(x1 + ffn) -> xb
        add_ln<<<NTOK, 256, 0, stream>>>(kb, ob,
            gamma + (size_t)l * kD, beta + (size_t)l * kD, xb);
    }

    mean_s<<<dim3(kD / 256, kB), 256, 0, stream>>>(xb, out);
}

// Round 2
// 3340.984 us; speedup vs baseline: 6.3202x; 6.3202x over previous
//
#include <hip/hip_runtime.h>
#include <hip/hip_bf16.h>
#include <math.h>

typedef unsigned short u16;
using bf16x8 = __attribute__((ext_vector_type(8))) short;
using f32x4  = __attribute__((ext_vector_type(4))) float;

static constexpr int kD = 768;
static constexpr int kH = 12;
static constexpr int kL = 6;
static constexpr int kF = 3072;
static constexpr int kS = 2048;
static constexpr int kB = 4;

__device__ __forceinline__ u16 f2bf(float f) {
    return __bfloat16_as_ushort(__float2bfloat16(f));
}

__device__ __forceinline__ void gload16(const void* g, void* l) {
    auto gp = reinterpret_cast<const __attribute__((address_space(1))) unsigned int*>(
        reinterpret_cast<uintptr_t>(g));
    auto lp = reinterpret_cast<__attribute__((address_space(3))) unsigned int*>(
        reinterpret_cast<uintptr_t>(l));
    __builtin_amdgcn_global_load_lds(gp, lp, 16, 0, 0);
}

// ---------------------------------------------------------------------------
// Embedding + sinusoidal PE; dual-writes f32 residual stream + bf16 copy
// ---------------------------------------------------------------------------
__global__ __launch_bounds__(256) void embed_pe(
    const int* __restrict__ ids, const float* __restrict__ emb,
    float* __restrict__ x, u16* __restrict__ xbf)
{
    const int t = blockIdx.x;
    const int s = t & (kS - 1);
    const int id = ids[t];
#pragma unroll
    for (int j = 0; j < 3; ++j) {
        const int d = threadIdx.x + (j << 8);
        const float i2 = (float)((d >> 1) << 1);
        const float dv = __expf(i2 * (-9.210340371976184f / 768.f));
        const float ang = (float)s * dv;
        const float pe = (d & 1) ? cosf(ang) : sinf(ang);
        const float v = emb[(size_t)id * kD + d] + pe;
        x[(size_t)t * kD + d] = v;
        if (xbf) xbf[(size_t)t * kD + d] = f2bf(v);
    }
}

// mask bias: -1e9 where ids==1 else 0
__global__ __launch_bounds__(256) void mk_mask(const int* __restrict__ ids,
                                               float* __restrict__ mb)
{
    const int i = blockIdx.x * 256 + threadIdx.x;
    if (i < kB * kS) mb[i] = (ids[i] == 1) ? -1e9f : 0.f;
}

// ---------------------------------------------------------------------------
// W[K][N] f32 -> Wt[N][K] bf16 (transpose + convert), 64x64 tiles
// grid: (K/64, N/64)
// ---------------------------------------------------------------------------
__global__ __launch_bounds__(256) void cvt_wT(
    const float* __restrict__ W, u16* __restrict__ Wt, int K, int N)
{
    __shared__ float T[64][68];
    const int k0 = blockIdx.x << 6, n0 = blockIdx.y << 6;
    const int tid = threadIdx.x;
#pragma unroll
    for (int i = 0; i < 4; ++i) {
        const int idx = tid + (i << 8);
        const int kr = idx >> 4;
        const int nc = (idx & 15) << 2;
        const float4 v = *(const float4*)(W + (size_t)(k0 + kr) * N + n0 + nc);
        T[kr][nc] = v.x; T[kr][nc + 1] = v.y; T[kr][nc + 2] = v.z; T[kr][nc + 3] = v.w;
    }
    __syncthreads();
#pragma unroll
    for (int i = 0; i < 4; ++i) {
        const int idx = tid + (i << 8);
        const int nr = idx >> 4;
        const int kc = (idx & 15) << 2;
        ushort4 o;
        o.x = f2bf(T[kc][nr]); o.y = f2bf(T[kc + 1][nr]);
        o.z = f2bf(T[kc + 2][nr]); o.w = f2bf(T[kc + 3][nr]);
        *(ushort4*)(Wt + (size_t)(n0 + nr) * K + k0 + kc) = o;
    }
}

// ---------------------------------------------------------------------------
// bf16 MFMA GEMM: C[M,N] = A[M,K] @ Bt[N,K]^T + bias
// 128x128 tile, BK=32, 256 thr (2x2 waves, 4x4 16x16 frags each).
// global_load_lds staging with pre-swizzled source granule (m173 pattern).
// mode: 0 = f32 out, 1 = bf16 out, 2 = bf16 out + ReLU
// ---------------------------------------------------------------------------
__global__ __launch_bounds__(256) void gemm_bf16(
    const u16* __restrict__ A, const u16* __restrict__ Bt,
    const float* __restrict__ bias, void* __restrict__ Cv,
    int M, int N, int K, int mode)
{
    __shared__ u16 As[4096];
    __shared__ u16 Bs[4096];
    const int tid = threadIdx.x;
    const int l = tid & 63;
    const int lo = l & 15, hi = l >> 4;
    const int w = tid >> 6, wr = w >> 1, wc = w & 1;
    const size_t row0 = (size_t)blockIdx.x * 128;
    const size_t col0 = (size_t)blockIdx.y * 128;

    // staging chunks: tid and tid+256 of 512 x 16B; LDS dest linear,
    // global source granule XOR-swizzled so frag reads are ~2-way.
    const int c0 = tid, c1 = tid + 256;
    const int r0 = c0 >> 2, g0 = (c0 & 3) ^ ((r0 >> 1) & 3);
    const int r1 = c1 >> 2, g1 = (c1 & 3) ^ ((r1 >> 1) & 3);
    const u16* a0 = A  + (row0 + r0) * K + g0 * 8;
    const u16* a1 = A  + (row0 + r1) * K + g1 * 8;
    const u16* b0 = Bt + (col0 + r0) * K + g0 * 8;
    const u16* b1 = Bt + (col0 + r1) * K + g1 * 8;
    u16* sa0 = As + c0 * 8; u16* sa1 = As + c1 * 8;
    u16* sb0 = Bs + c0 * 8; u16* sb1 = Bs + c1 * 8;

    f32x4 acc[4][4];
#pragma unroll
    for (int i = 0; i < 4; ++i)
#pragma unroll
        for (int j = 0; j < 4; ++j)
#pragma unroll
            for (int r = 0; r < 4; ++r) acc[i][j][r] = 0.f;

    int aoff[4], boff[4];
#pragma unroll
    for (int i = 0; i < 4; ++i) {
        const int ra = wr * 64 + i * 16 + lo;
        aoff[i] = ra * 32 + ((hi ^ ((ra >> 1) & 3)) << 3);
        const int rb = wc * 64 + i * 16 + lo;
        boff[i] = rb * 32 + ((hi ^ ((rb >> 1) & 3)) << 3);
    }

    for (int k0 = 0; k0 < K; k0 += 32) {
        __syncthreads();
        gload16(a0 + k0, sa0);
        gload16(a1 + k0, sa1);
        gload16(b0 + k0, sb0);
        gload16(b1 + k0, sb1);
        __syncthreads();
        bf16x8 af[4], bfr[4];
#pragma unroll
        for (int i = 0; i < 4; ++i) af[i] = *(const bf16x8*)&As[aoff[i]];
#pragma unroll
        for (int j = 0; j < 4; ++j) bfr[j] = *(const bf16x8*)&Bs[boff[j]];
#pragma unroll
        for (int i = 0; i < 4; ++i)
#pragma unroll
            for (int j = 0; j < 4; ++j)
                acc[i][j] = __builtin_amdgcn_mfma_f32_16x16x32_bf16(
                    af[i], bfr[j], acc[i][j], 0, 0, 0);
    }

#pragma unroll
    for (int i = 0; i < 4; ++i) {
        const size_t rbase = row0 + wr * 64 + i * 16 + hi * 4;
#pragma unroll
        for (int j = 0; j < 4; ++j) {
            const size_t c = col0 + wc * 64 + j * 16 + lo;
            const float bs = bias[c];
#pragma unroll
            for (int r = 0; r < 4; ++r) {
                float v = acc[i][j][r] + bs;
                if (mode == 2) v = fmaxf(v, 0.f);
                const size_t off = (rbase + r) * (size_t)N + c;
                if (mode == 0) ((float*)Cv)[off] = v;
                else           ((u16*)Cv)[off]  = f2bf(v);
            }
        }
    }
}

// ---------------------------------------------------------------------------
// MFMA flash attention, bf16 in/out. Block: 4 waves, 64 q-rows per block
// (16 per wave); K-tiles of 64 keys staged in swizzled LDS.
// Grid: (S/64, H, B).
// Swizzles (all keep 16B alignment of b128 ops, ~2-way banks):
//   Ks [key][64]: elem = key*64 + (e ^ ((key&7)<<3))
//   Vt [dim][64keys]: elem = d*64 + (key ^ (svz(d)<<3)), svz=(d&7)^((d>>3)&7)
//   Ps [q][64keys] per-wave: elem = q*64 + (key ^ (spz(q)<<3)), spz=(q&7)^((q>>3)<<1)
// ---------------------------------------------------------------------------
__global__ __launch_bounds__(256) void attn_mfma(
    const u16* __restrict__ Q, const u16* __restrict__ Kb,
    const u16* __restrict__ Vb, const float* __restrict__ mb,
    u16* __restrict__ O)
{
    __shared__ u16 Ks[64 * 64];
    __shared__ u16 Vt[64 * 64];
    __shared__ u16 Ps[4 * 16 * 64];
    __shared__ float Mb[kS];

    const int tid = threadIdx.x, l = tid & 63, w = tid >> 6;
    const int lo = l & 15, hi = l >> 4;
    const int h = blockIdx.y, b = blockIdx.z;
    const int q0 = blockIdx.x << 6;

    // stage mask bias row for this batch
#pragma unroll
    for (int i = 0; i < 2; ++i) {
        const int idx = (tid + (i << 8)) << 2;
        *(float4*)&Mb[idx] = *(const float4*)&mb[b * kS + idx];
    }

    // Q fragments: rows q0 + w*16 + lo, two K-steps of 32 dims
    bf16x8 qf[2];
    {
        const u16* qp = Q + ((size_t)(b * kS + q0 + w * 16 + lo)) * kD + h * 64 + hi * 8;
        qf[0] = *(const bf16x8*)qp;
        qf[1] = *(const bf16x8*)(qp + 32);
    }

    f32x4 accO[4];
    float mr[4], lr[4];
#pragma unroll
    for (int n = 0; n < 4; ++n)
#pragma unroll
        for (int r = 0; r < 4; ++r) accO[n][r] = 0.f;
#pragma unroll
    for (int r = 0; r < 4; ++r) { mr[r] = -3.0e38f; lr[r] = 0.f; }

    for (int kt = 0; kt < kS / 64; ++kt) {
        // ---- stage K (row-major swizzled) + V (transposed swizzled) ----
#pragma unroll
        for (int i = 0; i < 2; ++i) {
            const int lin = tid + (i << 8);          // 0..511
            const int key = lin >> 3;
            const int e0 = (lin & 7) << 3;
            const size_t gro = ((size_t)(b * kS + (kt << 6) + key)) * kD + h * 64 + e0;
            union { uint4 u; u16 s[8]; } kv, vv;
            kv.u = *(const uint4*)(Kb + gro);
            vv.u = *(const uint4*)(Vb + gro);
            *(uint4*)&Ks[key * 64 + (e0 ^ ((key & 7) << 3))] = kv.u;
#pragma unroll
            for (int e = 0; e < 8; ++e) {
                const int d = e0 + e;
                const int svz = (d & 7) ^ ((d >> 3) & 7);
                Vt[d * 64 + (key ^ (svz << 3))] = vv.s[e];
            }
        }
        __syncthreads();

        // ---- scores: per wave 16 q-rows x 64 keys ----
        f32x4 sf[4];
#pragma unroll
        for (int j = 0; j < 4; ++j) {
#pragma unroll
            for (int r = 0; r < 4; ++r) sf[j][r] = 0.f;
            const int key = j * 16 + lo;
            const int sw = (key & 7) << 3;
            const bf16x8 k0f = *(const bf16x8*)&Ks[key * 64 + ((hi * 8) ^ sw)];
            const bf16x8 k1f = *(const bf16x8*)&Ks[key * 64 + ((hi * 8 + 32) ^ sw)];
            sf[j] = __builtin_amdgcn_mfma_f32_16x16x32_bf16(qf[0], k0f, sf[j], 0, 0, 0);
            sf[j] = __builtin_amdgcn_mfma_f32_16x16x32_bf16(qf[1], k1f, sf[j], 0, 0, 0);
        }

        // ---- online softmax (rows q = hi*4 + r live in 16-lane groups) ----
        float p[4][4], corr[4], tmax[4], tsum[4];
#pragma unroll
        for (int r = 0; r < 4; ++r) tmax[r] = -3.0e38f;
#pragma unroll
        for (int j = 0; j < 4; ++j) {
            const float bj = Mb[(kt << 6) + j * 16 + lo];
#pragma unroll
            for (int r = 0; r < 4; ++r) {
                const float s = sf[j][r] * 0.125f + bj;
                p[j][r] = s;
                tmax[r] = fmaxf(tmax[r], s);
            }
        }
#pragma unroll
        for (int r = 0; r < 4; ++r) {
            float t = tmax[r];
            t = fmaxf(t, __shfl_xor(t, 1));
            t = fmaxf(t, __shfl_xor(t, 2));
            t = fmaxf(t, __shfl_xor(t, 4));
            t = fmaxf(t, __shfl_xor(t, 8));
            const float mn = fmaxf(mr[r], t);
            corr[r] = __expf(mr[r] - mn);
            mr[r] = mn;
            tsum[r] = 0.f;
        }
#pragma unroll
        for (int j = 0; j < 4; ++j)
#pragma unroll
            for (int r = 0; r < 4; ++r) {
                p[j][r] = __expf(p[j][r] - mr[r]);
                tsum[r] += p[j][r];
            }
#pragma unroll
        for (int r = 0; r < 4; ++r) {
            float t = tsum[r];
            t += __shfl_xor(t, 1);
            t += __shfl_xor(t, 2);
            t += __shfl_xor(t, 4);
            t += __shfl_xor(t, 8);
            lr[r] = lr[r] * corr[r] + t;
        }
#pragma unroll
        for (int n = 0; n < 4; ++n)
#pragma unroll
            for (int r = 0; r < 4; ++r) accO[n][r] *= corr[r];

        // ---- P -> bf16 via wave-private LDS round-trip ----
        u16* Pw = Ps + (w << 10);
#pragma unroll
        for (int j = 0; j < 4; ++j)
#pragma unroll
            for (int r = 0; r < 4; ++r) {
                const int q = hi * 4 + r;
                const int key = j * 16 + lo;
                const int spz = (q & 7) ^ ((q >> 3) << 1);
                Pw[q * 64 + (key ^ (spz << 3))] = f2bf(p[j][r]);
            }
        const int spq = (lo & 7) ^ ((lo >> 3) << 1);
        const bf16x8 pa0 = *(const bf16x8*)&Pw[lo * 64 + ((hi * 8) ^ (spq << 3))];
        const bf16x8 pa1 = *(const bf16x8*)&Pw[lo * 64 + ((hi * 8 + 32) ^ (spq << 3))];

        // ---- PV ----
#pragma unroll
        for (int n = 0; n < 4; ++n) {
            const int d = n * 16 + lo;
            const int svz = (d & 7) ^ ((d >> 3) & 7);
            const bf16x8 v0f = *(const bf16x8*)&Vt[d * 64 + ((hi * 8) ^ (svz << 3))];
            const bf16x8 v1f = *(const bf16x8*)&Vt[d * 64 + ((hi * 8 + 32) ^ (svz << 3))];
            accO[n] = __builtin_amdgcn_mfma_f32_16x16x32_bf16(pa0, v0f, accO[n], 0, 0, 0);
            accO[n] = __builtin_amdgcn_mfma_f32_16x16x32_bf16(pa1, v1f, accO[n], 0, 0, 0);
        }
        __syncthreads();   // all waves done with Ks/Vt before restage
    }

#pragma unroll
    for (int n = 0; n < 4; ++n)
#pragma unroll
        for (int r = 0; r < 4; ++r) {
            const int q = hi * 4 + r;
            O[((size_t)(b * kS + q0 + w * 16 + q)) * kD + h * 64 + n * 16 + lo] =
                f2bf(accO[n][r] / lr[r]);
        }
}

// ---------------------------------------------------------------------------
// out = LayerNorm(a + r); dual-writes f32 (+ optional bf16)
// ---------------------------------------------------------------------------
__device__ __forceinline__ float block_sum(float v, float* red)
{
#pragma unroll
    for (int off = 32; off; off >>= 1) v += __shfl_xor(v, off);
    __syncthreads();
    if ((threadIdx.x & 63) == 0) red[threadIdx.x >> 6] = v;
    __syncthreads();
    return red[0] + red[1] + red[2] + red[3];
}

__global__ __launch_bounds__(256) void add_ln(
    const float* __restrict__ a, const float* __restrict__ r,
    const float* __restrict__ g, const float* __restrict__ bt,
    float* __restrict__ out, u16* __restrict__ outb)
{
    __shared__ float red[4];
    const size_t row = blockIdx.x;
    const int tid = threadIdx.x;
    float v[3];
    float s = 0.f;
#pragma unroll
    for (int j = 0; j < 3; ++j) {
        const int d = tid + (j << 8);
        v[j] = a[row * kD + d] + r[row * kD + d];
        s += v[j];
    }
    s = block_sum(s, red);
    const float mu = s * (1.f / 768.f);
    float vs = 0.f;
#pragma unroll
    for (int j = 0; j < 3; ++j) { const float t = v[j] - mu; vs = fmaf(t, t, vs); }
    vs = block_sum(vs, red);
    const float rstd = rsqrtf(vs * (1.f / 768.f) + 1e-5f);
#pragma unroll
    for (int j = 0; j < 3; ++j) {
        const int d = tid + (j << 8);
        const float o = (v[j] - mu) * rstd * g[d] + bt[d];
        out[row * kD + d] = o;
        if (outb) outb[row * kD + d] = f2bf(o);
    }
}

__global__ __launch_bounds__(256) void mean_s(
    const float* __restrict__ x, float* __restrict__ out)
{
    const int d = blockIdx.x * 256 + threadIdx.x;
    const int b = blockIdx.y;
    float s = 0.f;
    for (int t = 0; t < kS; ++t) s += x[((size_t)b * kS + t) * kD + d];
    out[b * kD + d] = s * (1.f / 2048.f);
}

// ---------------------------------------------------------------------------
// FALLBACK (round-1 f32 path) — used only if ws_size is too small
// ---------------------------------------------------------------------------
__global__ __launch_bounds__(256) void gemm_f32(
    const float* __restrict__ A, const float* __restrict__ W,
    const float* __restrict__ bias, float* __restrict__ C,
    int M, int N, int K, int relu)
{
    __shared__ float As[16][68];
    __shared__ float Bs[16][68];
    const int tid = threadIdx.x;
    const int row0 = blockIdx.x << 6;
    const int col0 = blockIdx.y << 6;
    const int tx = tid & 15, ty = tid >> 4;
    const int ar = tid >> 2;
    const int ak = (tid & 3) << 2;
    const int bk = tid >> 4;
    const int bc = (tid & 15) << 2;
    float acc[4][4] = {};
    const float* Ap = A + (size_t)(row0 + ar) * K + ak;
    const float* Wp = W + (size_t)bk * N + col0 + bc;
    for (int k0 = 0; k0 < K; k0 += 16) {
        const float4 a4 = *(const float4*)(Ap + k0);
        const float4 b4 = *(const float4*)(Wp + (size_t)k0 * N);
        __syncthreads();
        As[ak + 0][ar] = a4.x; As[ak + 1][ar] = a4.y;
        As[ak + 2][ar] = a4.z; As[ak + 3][ar] = a4.w;
        *(float4*)&Bs[bk][bc] = b4;
        __syncthreads();
#pragma unroll
        for (int kk = 0; kk < 16; ++kk) {
            const float4 av = *(const float4*)&As[kk][ty << 2];
            const float4 bv = *(const float4*)&Bs[kk][tx << 2];
            const float aa[4] = {av.x, av.y, av.z, av.w};
            const float bb[4] = {bv.x, bv.y, bv.z, bv.w};
#pragma unroll
            for (int i = 0; i < 4; ++i)
#pragma unroll
                for (int j = 0; j < 4; ++j)
                    acc[i][j] = fmaf(aa[i], bb[j], acc[i][j]);
        }
    }
#pragma unroll
    for (int i = 0; i < 4; ++i) {
        const int row = row0 + (ty << 2) + i;
#pragma unroll
        for (int j = 0; j < 4; ++j) {
            const int col = col0 + (tx << 2) + j;
            float v = acc[i][j] + bias[col];
            if (relu) v = fmaxf(v, 0.f);
            C[(size_t)row * N + col] = v;
        }
    }
}

__global__ __launch_bounds__(256) void attn_fused(
    const float* __restrict__ Q, const float* __restrict__ Km,
    const float* __restrict__ Vm, const int* __restrict__ ids,
    float* __restrict__ O)
{
    __shared__ float Ksf[64 * 64];
    __shared__ float Vtf[64 * 64];
    __shared__ float Qs[16][64];
    __shared__ float Psf[4][4][64];
    const int tid = threadIdx.x;
    const int w = tid >> 6;
    const int lane = tid & 63;
    const int h = blockIdx.y, b = blockIdx.z;
    const int qrow0 = blockIdx.x << 4;
    {
        const int r = tid >> 4;
        const int c4 = tid & 15;
        const float4 q4 = *(const float4*)(
            Q + ((size_t)(b * kS + qrow0 + r)) * kD + h * 64 + (c4 << 2));
        Qs[r][(c4 << 2) + 0] = q4.x * 0.125f;
        Qs[r][(c4 << 2) + 1] = q4.y * 0.125f;
        Qs[r][(c4 << 2) + 2] = q4.z * 0.125f;
        Qs[r][(c4 << 2) + 3] = q4.w * 0.125f;
    }
    float m[4], lsum[4], o[4];
#pragma unroll
    for (int r = 0; r < 4; ++r) { m[r] = -3.0e38f; lsum[r] = 0.f; o[r] = 0.f; }
    for (int kt = 0; kt < kS / 64; ++kt) {
        __syncthreads();
#pragma unroll
        for (int i = 0; i < 4; ++i) {
            const int lin = tid + (i << 8);
            const int row = lin >> 4;
            const int s4 = lin & 15;
            const size_t gro = ((size_t)(b * kS + (kt << 6) + row)) * kD + h * 64 + (s4 << 2);
            const float4 k4 = *(const float4*)(Km + gro);
            ((float4*)Ksf)[(row << 4) + (s4 ^ (row & 7))] = k4;
            const float4 v4 = *(const float4*)(Vm + gro);
            const int ksl = row >> 2, ke = row & 3;
            const int d0 = s4 << 2;
            Vtf[(d0 + 0) * 64 + ((ksl ^ ((d0 + 0) & 7)) << 2) + ke] = v4.x;
            Vtf[(d0 + 1) * 64 + ((ksl ^ ((d0 + 1) & 7)) << 2) + ke] = v4.y;
            Vtf[(d0 + 2) * 64 + ((ksl ^ ((d0 + 2) & 7)) << 2) + ke] = v4.z;
            Vtf[(d0 + 3) * 64 + ((ksl ^ ((d0 + 3) & 7)) << 2) + ke] = v4.w;
        }
        __syncthreads();
        const bool masked = (ids[(size_t)b * kS + (kt << 6) + lane] == 1);
        float scr[4] = {0.f, 0.f, 0.f, 0.f};
#pragma unroll
        for (int i16 = 0; i16 < 16; ++i16) {
            const float4 kv = ((const float4*)Ksf)[(lane << 4) + (i16 ^ (lane & 7))];
#pragma unroll
            for (int r = 0; r < 4; ++r) {
                const float4 qv = *(const float4*)&Qs[(w << 2) + r][i16 << 2];
                scr[r] = fmaf(kv.x, qv.x, fmaf(kv.y, qv.y,
                          fmaf(kv.z, qv.z, fmaf(kv.w, qv.w, scr[r]))));
            }
        }
#pragma unroll
        for (int r = 0; r < 4; ++r) {
            float sm = masked ? -3.0e38f : scr[r];
#pragma unroll
            for (int off = 32; off; off >>= 1) sm = fmaxf(sm, __shfl_xor(sm, off));
            const float mn = fmaxf(m[r], sm);
            const float cr = __expf(m[r] - mn);
            const float pv = masked ? 0.f : __expf(scr[r] - mn);
            float ps = pv;
#pragma unroll
            for (int off = 32; off; off >>= 1) ps += __shfl_xor(ps, off);
            lsum[r] = lsum[r] * cr + ps;
            o[r] *= cr;
            m[r] = mn;
            Psf[w][r][lane] = pv;
        }
#pragma unroll
        for (int i16 = 0; i16 < 16; ++i16) {
            const float4 vv = ((const float4*)Vtf)[(lane << 4) + (i16 ^ (lane & 7))];
#pragma unroll
            for (int r = 0; r < 4; ++r) {
                const float4 pv = *(const float4*)&Psf[w][r][i16 << 2];
                o[r] = fmaf(pv.x, vv.x, fmaf(pv.y, vv.y,
                        fmaf(pv.z, vv.z, fmaf(pv.w, vv.w, o[r]))));
            }
        }
    }
#pragma unroll
    for (int r = 0; r < 4; ++r)
        O[((size_t)(b * kS + qrow0 + (w << 2) + r)) * kD + h * 64 + lane] =
            o[r] / lsum[r];
}

// ---------------------------------------------------------------------------
// Host orchestration
// ---------------------------------------------------------------------------
extern "C" void kernel_launch(void* const* d_in, const int* in_sizes, int n_in,
                              void* d_out, int out_size, void* d_ws, size_t ws_size,
                              hipStream_t stream)
{
    const int*   ids   = (const int*)  d_in[0];
    const float* emb   = (const float*)d_in[1];
    const float* Wq    = (const float*)d_in[2];
    const float* bq    = (const float*)d_in[3];
    const float* Wk    = (const float*)d_in[4];
    const float* bk    = (const float*)d_in[5];
    const float* Wv    = (const float*)d_in[6];
    const float* bv    = (const float*)d_in[7];
    const float* Wo    = (const float*)d_in[8];
    const float* bo    = (const float*)d_in[9];
    const float* W1    = (const float*)d_in[10];
    const float* b1    = (const float*)d_in[11];
    const float* W2    = (const float*)d_in[12];
    const float* b2    = (const float*)d_in[13];
    const float* gamma = (const float*)d_in[14];
    const float* beta  = (const float*)d_in[15];
    float* out = (float*)d_out;

    const size_t BUFE = (size_t)kB * kS * kD;            // 6,291,456
    const size_t WDD  = (size_t)kD * kD;                 // 589,824
    const size_t WDF  = (size_t)kD * kF;                 // 2,359,296
    const int NTOK = kB * kS;                            // 8192

    const size_t FAST_NEED = 3 * BUFE * 4 + 4 * BUFE * 2 +
                             (4 * WDD + 2 * WDF) * 2 + (size_t)NTOK * 4;

    if (ws_size >= FAST_NEED) {
        // -------- fast bf16 MFMA path --------
        float* xb  = (float*)d_ws;
        float* x1  = xb + BUFE;
        float* ob  = x1 + BUFE;
        u16*   abf = (u16*)(ob + BUFE);
        u16*   qbf = abf + BUFE;
        u16*   kbf = qbf + BUFE;
        u16*   vbf = kbf + BUFE;
        u16*   wqt = vbf + BUFE;
        u16*   wkt = wqt + WDD;
        u16*   wvt = wkt + WDD;
        u16*   wot = wvt + WDD;
        u16*   w1t = wot + WDD;
        u16*   w2t = w1t + WDF;
        float* mbf = (float*)(w2t + WDF);
        u16*   hbf = kbf;                                // hidden chunk (spans kbf+vbf)

        embed_pe<<<NTOK, 256, 0, stream>>>(ids, emb, xb, abf);
        mk_mask<<<NTOK / 256, 256, 0, stream>>>(ids, mbf);

        for (int l = 0; l < kL; ++l) {
            const size_t oDD = (size_t)l * WDD;
            const size_t oDF = (size_t)l * WDF;
            const float* bql = bq + (size_t)l * kD;
            const float* bkl = bk + (size_t)l * kD;
            const float* bvl = bv + (size_t)l * kD;
            const float* bol = bo + (size_t)l * kD;
            const float* b1l = b1 + (size_t)l * kF;
            const float* b2l = b2 + (size_t)l * kD;
            const float* gl  = gamma + (size_t)l * kD;
            const float* btl = beta  + (size_t)l * kD;

            cvt_wT<<<dim3(12, 12), 256, 0, stream>>>(Wq + oDD, wqt, kD, kD);
            cvt_wT<<<dim3(12, 12), 256, 0, stream>>>(Wk + oDD, wkt, kD, kD);
            cvt_wT<<<dim3(12, 12), 256, 0, stream>>>(Wv + oDD, wvt, kD, kD);
            cvt_wT<<<dim3(12, 12), 256, 0, stream>>>(Wo + oDD, wot, kD, kD);
            cvt_wT<<<dim3(12, 48), 256, 0, stream>>>(W1 + oDF, w1t, kD, kF);
            cvt_wT<<<dim3(48, 12), 256, 0, stream>>>(W2 + oDF, w2t, kF, kD);

            gemm_bf16<<<dim3(64, 6), 256, 0, stream>>>(abf, wqt, bql, qbf,
                NTOK, kD, kD, 1);
            gemm_bf16<<<dim3(64, 6), 256, 0, stream>>>(abf, wkt, bkl, kbf,
                NTOK, kD, kD, 1);
            gemm_bf16<<<dim3(64, 6), 256, 0, stream>>>(abf, wvt, bvl, vbf,
                NTOK, kD, kD, 1);

            attn_mfma<<<dim3(kS / 64, kH, kB), 256, 0, stream>>>(
                qbf, kbf, vbf, mbf, abf);                // attn out -> abf

            gemm_bf16<<<dim3(64, 6), 256, 0, stream>>>(abf, wot, bol, ob,
                NTOK, kD, kD, 0);

            add_ln<<<NTOK, 256, 0, stream>>>(xb, ob, gl, btl, x1, qbf);

            for (int c = 0; c < 2; ++c) {
                const size_t ro = (size_t)c * 4096;
                gemm_bf16<<<dim3(32, 24), 256, 0, stream>>>(
                    qbf + ro * kD, w1t, b1l, hbf, 4096, kF, kD, 2);
                gemm_bf16<<<dim3(32, 6), 256, 0, stream>>>(
                    hbf, w2t, b2l, ob + ro * kD, 4096, kD, kF, 0);
            }

            add_ln<<<NTOK, 256, 0, stream>>>(x1, ob, gl, btl, xb, abf);
        }

        mean_s<<<dim3(kD / 256, kB), 256, 0, stream>>>(xb, out);
        return;
    }

    // -------- fallback f32 path (round-1) --------
    if (ws_size < 5 * BUFE * sizeof(float)) return;
    float* xb = (float*)d_ws;
    float* kb = xb + BUFE;
    float* qb = kb + BUFE;
    float* vb = qb + BUFE;
    float* obf = vb + BUFE;
    float* hb = qb;

    embed_pe<<<NTOK, 256, 0, stream>>>(ids, emb, xb, nullptr);
    for (int l = 0; l < kL; ++l) {
        const size_t oDD = (size_t)l * WDD;
        const size_t oDF = (size_t)l * WDF;
        gemm_f32<<<dim3(NTOK / 64, kD / 64), 256, 0, stream>>>(
            xb, Wq + oDD, bq + (size_t)l * kD, qb, NTOK, kD, kD, 0);
        gemm_f32<<<dim3(NTOK / 64, kD / 64), 256, 0, stream>>>(
            xb, Wk + oDD, bk + (size_t)l * kD, kb, NTOK, kD, kD, 0);
        gemm_f32<<<dim3(NTOK / 64, kD / 64), 256, 0, stream>>>(
            xb, Wv + oDD, bv + (size_t)l * kD, vb, NTOK, kD, kD, 0);
        attn_fused<<<dim3(kS / 16, kH, kB), 256, 0, stream>>>(qb, kb, vb, ids, obf);
        gemm_f32<<<dim3(NTOK / 64, kD / 64), 256, 0, stream>>>(
            obf, Wo + oDD, bo + (size_t)l * kD, qb, NTOK, kD, kD, 0);
        add_ln<<<NTOK, 256, 0, stream>>>(xb, qb,
            gamma + (size_t)l * kD, beta + (size_t)l * kD, kb, nullptr);
        for (int c = 0; c < 2; ++c) {
            const size_t ro = (size_t)c * 4096;
            gemm_f32<<<dim3(4096 / 64, kF / 64), 256, 0, stream>>>(
                kb + ro * kD, W1 + oDF, b1 + (size_t)l * kF, hb, 4096, kF, kD, 1);
            gemm_f32<<<dim3(4096 / 64, kD / 64), 256, 0, stream>>>(
                hb, W2 + oDF, b2 + (size_t)l * kD, obf + ro * kD, 4096, kD, kF, 0);
        }
        add_ln<<<NTOK, 256, 0, stream>>>(kb, obf,
            gamma + (size_t)l * kD, beta + (size_t)l * kD, xb, nullptr);
    }
    mean_s<<<dim3(kD / 256, kB), 256, 0, stream>>>(xb, out);
}